// Round 1
// baseline (120.261 us; speedup 1.0000x reference)
//
#include <hip/hip_runtime.h>

#define IS2 0.7071067811865476f
#define C3F 0.35355339059327373f   // (1/sqrt(2))^3
#define TAU_F 0.05f
#define THIRD 0.3333333333333333f

// ------------------------------------------------------------------
// In-place 2D multilevel Haar on an 8x8 register tile.
// Temps are <=32 floats (vs the previous t[64]) so one slice needs
// ~m[64]+32 live VGPRs. Matches reference _haar2_fwd / _haar2_inv.
// ------------------------------------------------------------------
__device__ __forceinline__ void haar2_fwd(float (&m)[64]) {
    #pragma unroll
    for (int half = 4; half >= 1; half >>= 1) {
        const int sz = half * 2;
        // rows: pairs (2r,2r+1) -> lo at r (in place, safe), hi via temp
        float th[32];
        #pragma unroll
        for (int r = 0; r < half; ++r)
            #pragma unroll
            for (int c = 0; c < sz; ++c) {
                float a = m[(2*r)*8 + c], b = m[(2*r+1)*8 + c];
                m[r*8 + c] = (a + b) * IS2;
                th[r*8 + c] = (a - b) * IS2;
            }
        #pragma unroll
        for (int r = 0; r < half; ++r)
            #pragma unroll
            for (int c = 0; c < sz; ++c) m[(r+half)*8 + c] = th[r*8 + c];
        // cols: pairs (2c,2c+1) -> lo at c (in place, safe), hi via temp
        #pragma unroll
        for (int r = 0; r < sz; ++r) {
            float tw[4];
            #pragma unroll
            for (int c = 0; c < half; ++c) {
                float a = m[r*8 + 2*c], b = m[r*8 + 2*c + 1];
                m[r*8 + c] = (a + b) * IS2;
                tw[c]      = (a - b) * IS2;
            }
            #pragma unroll
            for (int c = 0; c < half; ++c) m[r*8 + c + half] = tw[c];
        }
    }
}

__device__ __forceinline__ void haar2_inv(float (&m)[64]) {
    #pragma unroll
    for (int sz = 2; sz <= 8; sz <<= 1) {
        const int half = sz >> 1;
        // horizontal inverse (per row, temp = sz floats)
        #pragma unroll
        for (int r = 0; r < sz; ++r) {
            float te[8];
            #pragma unroll
            for (int c = 0; c < half; ++c) {
                float lo = m[r*8 + c], hi = m[r*8 + c + half];
                te[2*c]   = (lo + hi) * IS2;
                te[2*c+1] = (lo - hi) * IS2;
            }
            #pragma unroll
            for (int k = 0; k < sz; ++k) m[r*8 + k] = te[k];
        }
        // vertical inverse (per column, temp = sz floats)
        #pragma unroll
        for (int c = 0; c < sz; ++c) {
            float tc[8];
            #pragma unroll
            for (int r = 0; r < half; ++r) {
                float lo = m[r*8 + c], hi = m[(r+half)*8 + c];
                tc[2*r]   = (lo + hi) * IS2;
                tc[2*r+1] = (lo - hi) * IS2;
            }
            #pragma unroll
            for (int r = 0; r < sz; ++r) m[r*8 + c] = tc[r];
        }
    }
}

// fwd -> soft-threshold (keep DC) -> inv on one 8x8 slice, in registers
__device__ __forceinline__ void bandlet_slice(float (&m)[64]) {
    haar2_fwd(m);
    float dc = m[0];
    #pragma unroll
    for (int e = 0; e < 64; ++e) {
        float v = m[e];
        float av = fabsf(v) - TAU_F;
        m[e] = av > 0.0f ? copysignf(av, v) : 0.0f;
    }
    m[0] = dc;
    haar2_inv(m);
}

// ------------------------------------------------------------------
// 3-wave blockproc on one 8^3 band block (PLAIN layout in LDS:
//   element (d,h,w) at Lb[d*64 + h*8 + w], band stride 516 dwords).
// Call with 192 threads (3 waves). wv = wave id = normal id:
//   wv0: slice d=s, keeps R0 in m (becomes accumulator)
//   wv1: slice h=s, writes R1 back into Lb (input is dead after loads)
//   wv2: slice w=s, scatters R2 into Rb
// After return, wv0&&act threads hold m = R0+R1+R2 for output slice s.
// ALL 192 threads must call (barriers inside); act=false threads idle.
// Bank behavior (verified layout): wv0/wv1 b128 = 8 dwords/bank uniform
// (b128 floor), wv2 b32 = 2-way = free.
// ------------------------------------------------------------------
__device__ __forceinline__ void blockproc3(float* __restrict__ Lb,
                                           float* __restrict__ Rb,
                                           int wv, int s, bool act,
                                           float (&m)[64]) {
    if (act) {
        if (wv == 0) {
            #pragma unroll
            for (int r = 0; r < 8; ++r) {
                float4 v0 = *(const float4*)&Lb[s*64 + r*8];
                float4 v1 = *(const float4*)&Lb[s*64 + r*8 + 4];
                m[r*8+0]=v0.x; m[r*8+1]=v0.y; m[r*8+2]=v0.z; m[r*8+3]=v0.w;
                m[r*8+4]=v1.x; m[r*8+5]=v1.y; m[r*8+6]=v1.z; m[r*8+7]=v1.w;
            }
        } else if (wv == 1) {
            #pragma unroll
            for (int r = 0; r < 8; ++r) {
                float4 v0 = *(const float4*)&Lb[r*64 + s*8];
                float4 v1 = *(const float4*)&Lb[r*64 + s*8 + 4];
                m[r*8+0]=v0.x; m[r*8+1]=v0.y; m[r*8+2]=v0.z; m[r*8+3]=v0.w;
                m[r*8+4]=v1.x; m[r*8+5]=v1.y; m[r*8+6]=v1.z; m[r*8+7]=v1.w;
            }
        } else {
            #pragma unroll
            for (int r = 0; r < 8; ++r)
                #pragma unroll
                for (int c = 0; c < 8; ++c)
                    m[r*8+c] = Lb[r*64 + c*8 + s];
        }
    }
    __syncthreads();          // all loads of Lb drained -> Lb reusable
    if (act) {
        bandlet_slice(m);
        if (wv == 1) {
            // R1 contribution lands at (i=r, j=s, k=c)
            #pragma unroll
            for (int r = 0; r < 8; ++r) {
                *(float4*)&Lb[r*64 + s*8]     = make_float4(m[r*8+0], m[r*8+1], m[r*8+2], m[r*8+3]);
                *(float4*)&Lb[r*64 + s*8 + 4] = make_float4(m[r*8+4], m[r*8+5], m[r*8+6], m[r*8+7]);
            }
        } else if (wv == 2) {
            // R2 contribution lands at (i=r, j=c, k=s)
            #pragma unroll
            for (int r = 0; r < 8; ++r)
                #pragma unroll
                for (int c = 0; c < 8; ++c)
                    Rb[r*64 + c*8 + s] = m[r*8+c];
        }
    }
    __syncthreads();          // R1/R2 visible
    if (act && wv == 0) {
        #pragma unroll
        for (int r = 0; r < 8; ++r) {
            float4 a0 = *(const float4*)&Lb[s*64 + r*8];
            float4 a1 = *(const float4*)&Lb[s*64 + r*8 + 4];
            float4 b0 = *(const float4*)&Rb[s*64 + r*8];
            float4 b1 = *(const float4*)&Rb[s*64 + r*8 + 4];
            m[r*8+0] += a0.x + b0.x; m[r*8+1] += a0.y + b0.y;
            m[r*8+2] += a0.z + b0.z; m[r*8+3] += a0.w + b0.w;
            m[r*8+4] += a1.x + b1.x; m[r*8+5] += a1.y + b1.y;
            m[r*8+6] += a1.z + b1.z; m[r*8+7] += a1.w + b1.w;
        }
    }
}

// ------------------------------------------------------------------
// Kernel A: fused level-1 forward DWT + level-1 blockproc.
// One wg (192 thr = 3 waves) = one 16^3 input tile.
// Grid: 2 * 10^3 = 2000 wgs. LDS = 2 * 7 * 516 * 4 = 28.9 KB.
// ------------------------------------------------------------------
__global__ __launch_bounds__(192, 4) void fwd1_bp(const float* __restrict__ x,
                                                  float* __restrict__ bands) {
    constexpr int LST = 516;
    constexpr size_t B1S = (size_t)2 * 80 * 80 * 80;
    __shared__ __align__(16) float lin[7 * LST];   // input bands 1..7, reused as R1
    __shared__ __align__(16) float lr2[7 * LST];   // R2

    const int t  = threadIdx.x;
    const int wg = blockIdx.x;
    const int b  = wg / 1000;
    const int tl = wg - b * 1000;
    const int td = tl / 100;
    const int rr = tl - td * 100;
    const int th = rr / 10;
    const int tw = rr - th * 10;

    const float* ip = x + ((size_t)(b*160 + 16*td)) * 25600 + (size_t)(16*th) * 160 + 16*tw;
    float* lllp = bands + ((size_t)(b*80 + 8*td)) * 6400 + (size_t)(8*th) * 80 + 8*tw;

    // ---- phase 1: level-1 forward, 512 output positions over 192 threads ----
    #pragma unroll
    for (int k = 0; k < 3; ++k) {
        const int p = t + k * 192;
        if (p < 512) {
            const int q = p >> 6, j = (p >> 3) & 7, w = p & 7;
            const float* pp = ip + (size_t)(2*q) * 25600 + (2*j) * 160 + 2*w;
            float2 q00 = *(const float2*)(pp);
            float2 q01 = *(const float2*)(pp + 160);
            float2 q10 = *(const float2*)(pp + 25600);
            float2 q11 = *(const float2*)(pp + 25600 + 160);
            float wl00 = q00.x + q00.y, wh00 = q00.x - q00.y;
            float wl01 = q01.x + q01.y, wh01 = q01.x - q01.y;
            float wl10 = q10.x + q10.y, wh10 = q10.x - q10.y;
            float wl11 = q11.x + q11.y, wh11 = q11.x - q11.y;
            float hl0l = wl00 + wl01, hh0l = wl00 - wl01;
            float hl0h = wh00 + wh01, hh0h = wh00 - wh01;
            float hl1l = wl10 + wl11, hh1l = wl10 - wl11;
            float hl1h = wh10 + wh11, hh1h = wh10 - wh11;
            const int pos = q*64 + j*8 + w;
            lin[0*LST + pos] = (hl0h + hl1h) * C3F;   // llh -> band 1
            lin[1*LST + pos] = (hh0l + hh1l) * C3F;   // lhl -> band 2
            lin[2*LST + pos] = (hh0h + hh1h) * C3F;   // lhh -> band 3
            lin[3*LST + pos] = (hl0l - hl1l) * C3F;   // hll -> band 4
            lin[4*LST + pos] = (hl0h - hl1h) * C3F;   // hlh -> band 5
            lin[5*LST + pos] = (hh0l - hh1l) * C3F;   // hhl -> band 6
            lin[6*LST + pos] = (hh0h - hh1h) * C3F;   // hhh -> band 7
            lllp[q*6400 + j*80 + w] = (hl0l + hl1l) * C3F;   // lll raw
        }
    }
    __syncthreads();

    // ---- phase 2: blockproc, 1 slice per thread, normal = wave id ----
    const int wv   = t >> 6;
    const int lane = t & 63;
    const int f    = lane >> 3;   // 0..7, band index (7 invalid)
    const int s    = lane & 7;
    const bool act = f < 7;
    const int fc   = act ? f : 0;

    float m[64];
    blockproc3(&lin[fc * LST], &lr2[fc * LST], wv, s, act, m);

    // ---- phase 3: wave0 writes processed band (f+1), slice d=s ----
    if (act && wv == 0) {
        float* gp = bands + (size_t)(f + 1) * B1S
                  + ((size_t)(b*80 + 8*td + s)) * 6400 + (size_t)(8*th) * 80 + 8*tw;
        #pragma unroll
        for (int jj = 0; jj < 8; ++jj) {
            float* qo = gp + jj * 80;
            *(float4*)(qo)     = make_float4(m[jj*8+0]*THIRD, m[jj*8+1]*THIRD,
                                             m[jj*8+2]*THIRD, m[jj*8+3]*THIRD);
            *(float4*)(qo + 4) = make_float4(m[jj*8+4]*THIRD, m[jj*8+5]*THIRD,
                                             m[jj*8+6]*THIRD, m[jj*8+7]*THIRD);
        }
    }
}

// ------------------------------------------------------------------
// Kernel B: fused level-2 forward + blockproc + level-2 inverse,
// in place on lll1 (= bands[0], shape (2,80,80,80)).
// One wg (192 thr) = one 16^3 tile of lll1. Grid: 2 * 5^3 = 250 wgs.
// LDS = (8+7) * 516 * 4 = 31 KB.
// ------------------------------------------------------------------
__global__ __launch_bounds__(192, 4) void l2_pipeline(float* __restrict__ lll) {
    constexpr int LST = 516;
    __shared__ __align__(16) float lin[8 * LST];   // bands 0..7 (0 = lll2 raw)
    __shared__ __align__(16) float lr2[7 * LST];

    const int t  = threadIdx.x;
    const int wg = blockIdx.x;
    const int b  = wg / 125;
    const int tl = wg - b * 125;
    const int td = tl / 25;
    const int rr = tl - td * 25;
    const int th = rr / 5;
    const int tw = rr - th * 5;

    float* base = lll + ((size_t)(b*80 + 16*td)) * 6400 + (size_t)(16*th) * 80 + 16*tw;

    // ---- phase 1: level-2 forward, all 8 bands into LDS ----
    #pragma unroll
    for (int k = 0; k < 3; ++k) {
        const int p = t + k * 192;
        if (p < 512) {
            const int q = p >> 6, j = (p >> 3) & 7, w = p & 7;
            const float* pp = base + (size_t)(2*q) * 6400 + (2*j) * 80 + 2*w;
            float2 q00 = *(const float2*)(pp);
            float2 q01 = *(const float2*)(pp + 80);
            float2 q10 = *(const float2*)(pp + 6400);
            float2 q11 = *(const float2*)(pp + 6400 + 80);
            float wl00 = q00.x + q00.y, wh00 = q00.x - q00.y;
            float wl01 = q01.x + q01.y, wh01 = q01.x - q01.y;
            float wl10 = q10.x + q10.y, wh10 = q10.x - q10.y;
            float wl11 = q11.x + q11.y, wh11 = q11.x - q11.y;
            float hl0l = wl00 + wl01, hh0l = wl00 - wl01;
            float hl0h = wh00 + wh01, hh0h = wh00 - wh01;
            float hl1l = wl10 + wl11, hh1l = wl10 - wl11;
            float hl1h = wh10 + wh11, hh1h = wh10 - wh11;
            const int pos = q*64 + j*8 + w;
            lin[0*LST + pos] = (hl0l + hl1l) * C3F;   // lll2 (kept raw)
            lin[1*LST + pos] = (hl0h + hl1h) * C3F;
            lin[2*LST + pos] = (hh0l + hh1l) * C3F;
            lin[3*LST + pos] = (hh0h + hh1h) * C3F;
            lin[4*LST + pos] = (hl0l - hl1l) * C3F;
            lin[5*LST + pos] = (hl0h - hl1h) * C3F;
            lin[6*LST + pos] = (hh0l - hh1l) * C3F;
            lin[7*LST + pos] = (hh0h - hh1h) * C3F;
        }
    }
    __syncthreads();

    // ---- phase 2: blockproc bands 1..7 ----
    const int wv   = t >> 6;
    const int lane = t & 63;
    const int f    = lane >> 3;
    const int s    = lane & 7;
    const bool act = f < 7;

    float m[64];
    blockproc3(&lin[(act ? f + 1 : 1) * LST], &lr2[(act ? f : 0) * LST], wv, s, act, m);

    // wave0 writes processed/3 back into lin[band], slice d=s
    // (each element read (R1) and written by the same thread only)
    if (act && wv == 0) {
        float* Lb = &lin[(f + 1) * LST];
        #pragma unroll
        for (int r = 0; r < 8; ++r) {
            *(float4*)&Lb[s*64 + r*8]     = make_float4(m[r*8+0]*THIRD, m[r*8+1]*THIRD,
                                                        m[r*8+2]*THIRD, m[r*8+3]*THIRD);
            *(float4*)&Lb[s*64 + r*8 + 4] = make_float4(m[r*8+4]*THIRD, m[r*8+5]*THIRD,
                                                        m[r*8+6]*THIRD, m[r*8+7]*THIRD);
        }
    }
    __syncthreads();

    // ---- phase 3: level-2 inverse, write back in place ----
    #pragma unroll
    for (int k = 0; k < 3; ++k) {
        const int p = t + k * 192;
        if (p < 512) {
            const int q = p >> 6, j = (p >> 3) & 7, w = p & 7;
            const int pos = q*64 + j*8 + w;
            float b0 = lin[0*LST + pos], b1 = lin[1*LST + pos];
            float b2 = lin[2*LST + pos], b3 = lin[3*LST + pos];
            float b4 = lin[4*LST + pos], b5 = lin[5*LST + pos];
            float b6 = lin[6*LST + pos], b7 = lin[7*LST + pos];
            float c0 = b0 + b4, c1 = b1 + b5, c2 = b2 + b6, c3 = b3 + b7;
            float c4 = b0 - b4, c5 = b1 - b5, c6 = b2 - b6, c7 = b3 - b7;
            float e00 = c0 + c2, e01 = c1 + c3;
            float e02 = c0 - c2, e03 = c1 - c3;
            float e10 = c4 + c6, e11 = c5 + c7;
            float e12 = c4 - c6, e13 = c5 - c7;
            float* pp = base + (size_t)(2*q) * 6400 + (2*j) * 80 + 2*w;
            *(float2*)(pp)             = make_float2((e00+e01)*C3F, (e00-e01)*C3F);
            *(float2*)(pp + 80)        = make_float2((e02+e03)*C3F, (e02-e03)*C3F);
            *(float2*)(pp + 6400)      = make_float2((e10+e11)*C3F, (e10-e11)*C3F);
            *(float2*)(pp + 6400 + 80) = make_float2((e12+e13)*C3F, (e12-e13)*C3F);
        }
    }
}

// ------------------------------------------------------------------
// Kernel C: level-1 inverse, 8 bands (2,80^3) -> out (2,160^3).
// 2-wide per thread: float2 band loads, float4 output stores.
// ------------------------------------------------------------------
__global__ __launch_bounds__(256) void dwt3_inv80(const float* __restrict__ bands,
                                                  float* __restrict__ out) {
    const int tid = blockIdx.x * blockDim.x + threadIdx.x;
    constexpr int S = 80;
    constexpr size_t bs_ = (size_t)2 * S * S * S;
    const size_t o = (size_t)tid * 2;
    const int w = (int)(o % S);
    const int h = (int)((o / S) % S);
    const int d = (int)((o / (S*S)) % S);
    const int b = (int)(o / ((size_t)S*S*S));

    float2 B0 = *(const float2*)&bands[0*bs_ + o];
    float2 B1 = *(const float2*)&bands[1*bs_ + o];
    float2 B2 = *(const float2*)&bands[2*bs_ + o];
    float2 B3 = *(const float2*)&bands[3*bs_ + o];
    float2 B4 = *(const float2*)&bands[4*bs_ + o];
    float2 B5 = *(const float2*)&bands[5*bs_ + o];
    float2 B6 = *(const float2*)&bands[6*bs_ + o];
    float2 B7 = *(const float2*)&bands[7*bs_ + o];

    float c0x = B0.x + B4.x, c1x = B1.x + B5.x, c2x = B2.x + B6.x, c3x = B3.x + B7.x;
    float c4x = B0.x - B4.x, c5x = B1.x - B5.x, c6x = B2.x - B6.x, c7x = B3.x - B7.x;
    float e00x = c0x + c2x, e01x = c1x + c3x, e02x = c0x - c2x, e03x = c1x - c3x;
    float e10x = c4x + c6x, e11x = c5x + c7x, e12x = c4x - c6x, e13x = c5x - c7x;

    float c0y = B0.y + B4.y, c1y = B1.y + B5.y, c2y = B2.y + B6.y, c3y = B3.y + B7.y;
    float c4y = B0.y - B4.y, c5y = B1.y - B5.y, c6y = B2.y - B6.y, c7y = B3.y - B7.y;
    float e00y = c0y + c2y, e01y = c1y + c3y, e02y = c0y - c2y, e03y = c1y - c3y;
    float e10y = c4y + c6y, e11y = c5y + c7y, e12y = c4y - c6y, e13y = c5y - c7y;

    float* p = out + (((size_t)b * 160 + 2*d) * 160 + 2*h) * 160 + 2*w;
    *(float4*)(p)               = make_float4((e00x+e01x)*C3F, (e00x-e01x)*C3F,
                                              (e00y+e01y)*C3F, (e00y-e01y)*C3F);
    *(float4*)(p + 160)         = make_float4((e02x+e03x)*C3F, (e02x-e03x)*C3F,
                                              (e02y+e03y)*C3F, (e02y-e03y)*C3F);
    *(float4*)(p + 25600)       = make_float4((e10x+e11x)*C3F, (e10x-e11x)*C3F,
                                              (e10y+e11y)*C3F, (e10y-e11y)*C3F);
    *(float4*)(p + 25600 + 160) = make_float4((e12x+e13x)*C3F, (e12x-e13x)*C3F,
                                              (e12y+e13y)*C3F, (e12y-e13y)*C3F);
}

// ------------------------------------------------------------------
// Pipeline (3 launches):
//   A: x (2,160^3) -> bands[0]=lll1 raw, bands[1..7] processed   [d_ws]
//   B: bands[0] -> fwd2 + blockproc + inv2, in place (LDS-resident)
//   C: bands[0..7] -> inverse level-1 -> d_out
// ------------------------------------------------------------------
extern "C" void kernel_launch(void* const* d_in, const int* in_sizes, int n_in,
                              void* d_out, int out_size, void* d_ws, size_t ws_size,
                              hipStream_t stream) {
    const float* x = (const float*)d_in[0];
    float* out = (float*)d_out;
    float* bands = (float*)d_ws;   // 8 * 2*80^3 floats = 32.77 MB

    fwd1_bp<<<2000, 192, 0, stream>>>(x, bands);
    l2_pipeline<<<250, 192, 0, stream>>>(bands);
    dwt3_inv80<<<2000, 256, 0, stream>>>(bands, out);
}

// Round 3
// 117.577 us; speedup vs baseline: 1.0228x; 1.0228x over previous
//
#include <hip/hip_runtime.h>

#define IS2 0.7071067811865476f
#define C3F 0.35355339059327373f   // (1/sqrt(2))^3
#define TAU_F 0.05f
#define THIRD 0.3333333333333333f

typedef float floatx4 __attribute__((ext_vector_type(4)));

// ------------------------------------------------------------------
// In-place 2D multilevel Haar on an 8x8 register tile (<=32-float temps).
// Matches reference _haar2_fwd / _haar2_inv.
// ------------------------------------------------------------------
__device__ __forceinline__ void haar2_fwd(float (&m)[64]) {
    #pragma unroll
    for (int half = 4; half >= 1; half >>= 1) {
        const int sz = half * 2;
        float th[32];
        #pragma unroll
        for (int r = 0; r < half; ++r)
            #pragma unroll
            for (int c = 0; c < sz; ++c) {
                float a = m[(2*r)*8 + c], b = m[(2*r+1)*8 + c];
                m[r*8 + c] = (a + b) * IS2;
                th[r*8 + c] = (a - b) * IS2;
            }
        #pragma unroll
        for (int r = 0; r < half; ++r)
            #pragma unroll
            for (int c = 0; c < sz; ++c) m[(r+half)*8 + c] = th[r*8 + c];
        #pragma unroll
        for (int r = 0; r < sz; ++r) {
            float tw[4];
            #pragma unroll
            for (int c = 0; c < half; ++c) {
                float a = m[r*8 + 2*c], b = m[r*8 + 2*c + 1];
                m[r*8 + c] = (a + b) * IS2;
                tw[c]      = (a - b) * IS2;
            }
            #pragma unroll
            for (int c = 0; c < half; ++c) m[r*8 + c + half] = tw[c];
        }
    }
}

__device__ __forceinline__ void haar2_inv(float (&m)[64]) {
    #pragma unroll
    for (int sz = 2; sz <= 8; sz <<= 1) {
        const int half = sz >> 1;
        #pragma unroll
        for (int r = 0; r < sz; ++r) {
            float te[8];
            #pragma unroll
            for (int c = 0; c < half; ++c) {
                float lo = m[r*8 + c], hi = m[r*8 + c + half];
                te[2*c]   = (lo + hi) * IS2;
                te[2*c+1] = (lo - hi) * IS2;
            }
            #pragma unroll
            for (int k = 0; k < sz; ++k) m[r*8 + k] = te[k];
        }
        #pragma unroll
        for (int c = 0; c < sz; ++c) {
            float tc[8];
            #pragma unroll
            for (int r = 0; r < half; ++r) {
                float lo = m[r*8 + c], hi = m[(r+half)*8 + c];
                tc[2*r]   = (lo + hi) * IS2;
                tc[2*r+1] = (lo - hi) * IS2;
            }
            #pragma unroll
            for (int r = 0; r < sz; ++r) m[r*8 + c] = tc[r];
        }
    }
}

__device__ __forceinline__ void bandlet_slice(float (&m)[64]) {
    haar2_fwd(m);
    float dc = m[0];
    #pragma unroll
    for (int e = 0; e < 64; ++e) {
        float v = m[e];
        float av = fabsf(v) - TAU_F;
        m[e] = av > 0.0f ? copysignf(av, v) : 0.0f;
    }
    m[0] = dc;
    haar2_inv(m);
}

// ------------------------------------------------------------------
// 3-wave blockproc on one 8^3 band block (PLAIN layout in LDS:
//   element (d,h,w) at Lb[d*64 + h*8 + w], band stride 516 dwords).
// wv0: slice d=s, keeps R0 in m (accumulator). wv1: slice h=s, writes
// R1 back into Lb. wv2: slice w=s, scatters R2 into Rb.
// After return, wv0&&act threads hold m = R0+R1+R2 for slice d=s.
// ALL 192 threads must call (barriers inside).
// ------------------------------------------------------------------
__device__ __forceinline__ void blockproc3(float* __restrict__ Lb,
                                           float* __restrict__ Rb,
                                           int wv, int s, bool act,
                                           float (&m)[64]) {
    if (act) {
        if (wv == 0) {
            #pragma unroll
            for (int r = 0; r < 8; ++r) {
                float4 v0 = *(const float4*)&Lb[s*64 + r*8];
                float4 v1 = *(const float4*)&Lb[s*64 + r*8 + 4];
                m[r*8+0]=v0.x; m[r*8+1]=v0.y; m[r*8+2]=v0.z; m[r*8+3]=v0.w;
                m[r*8+4]=v1.x; m[r*8+5]=v1.y; m[r*8+6]=v1.z; m[r*8+7]=v1.w;
            }
        } else if (wv == 1) {
            #pragma unroll
            for (int r = 0; r < 8; ++r) {
                float4 v0 = *(const float4*)&Lb[r*64 + s*8];
                float4 v1 = *(const float4*)&Lb[r*64 + s*8 + 4];
                m[r*8+0]=v0.x; m[r*8+1]=v0.y; m[r*8+2]=v0.z; m[r*8+3]=v0.w;
                m[r*8+4]=v1.x; m[r*8+5]=v1.y; m[r*8+6]=v1.z; m[r*8+7]=v1.w;
            }
        } else {
            #pragma unroll
            for (int r = 0; r < 8; ++r)
                #pragma unroll
                for (int c = 0; c < 8; ++c)
                    m[r*8+c] = Lb[r*64 + c*8 + s];
        }
    }
    __syncthreads();          // all loads of Lb drained -> Lb reusable
    if (act) {
        bandlet_slice(m);
        if (wv == 1) {
            #pragma unroll
            for (int r = 0; r < 8; ++r) {
                *(float4*)&Lb[r*64 + s*8]     = make_float4(m[r*8+0], m[r*8+1], m[r*8+2], m[r*8+3]);
                *(float4*)&Lb[r*64 + s*8 + 4] = make_float4(m[r*8+4], m[r*8+5], m[r*8+6], m[r*8+7]);
            }
        } else if (wv == 2) {
            #pragma unroll
            for (int r = 0; r < 8; ++r)
                #pragma unroll
                for (int c = 0; c < 8; ++c)
                    Rb[r*64 + c*8 + s] = m[r*8+c];
        }
    }
    __syncthreads();          // R1/R2 visible
    if (act && wv == 0) {
        #pragma unroll
        for (int r = 0; r < 8; ++r) {
            float4 a0 = *(const float4*)&Lb[s*64 + r*8];
            float4 a1 = *(const float4*)&Lb[s*64 + r*8 + 4];
            float4 b0 = *(const float4*)&Rb[s*64 + r*8];
            float4 b1 = *(const float4*)&Rb[s*64 + r*8 + 4];
            m[r*8+0] += a0.x + b0.x; m[r*8+1] += a0.y + b0.y;
            m[r*8+2] += a0.z + b0.z; m[r*8+3] += a0.w + b0.w;
            m[r*8+4] += a1.x + b1.x; m[r*8+5] += a1.y + b1.y;
            m[r*8+6] += a1.z + b1.z; m[r*8+7] += a1.w + b1.w;
        }
    }
}

// ==================================================================
// Intermediate band storage: BLOCK-NATIVE layout.
//   bands[ ((f*2 + b)*1000 + blk) * 512 + i*64 + j*8 + k ]
// where blk = Bd*100 + Bh*10 + Bw (Bd,Bh,Bw in [0,10)), (i,j,k) in [0,8).
// Every 8^3 block is 2 KB contiguous -> all producer writes are
// full-line, single-owner; all consumer reads are contiguous streams.
// ==================================================================

// ------------------------------------------------------------------
// Kernel A: fused level-1 forward DWT + level-1 blockproc.
// One wg (192 thr) = one 16^3 input tile. Grid: 2000.
// ------------------------------------------------------------------
__global__ __launch_bounds__(192, 4) void fwd1_bp(const float* __restrict__ x,
                                                  float* __restrict__ bands) {
    constexpr int LST = 516;
    __shared__ __align__(16) float lin[7 * LST];   // bands 1..7, reused as R1
    __shared__ __align__(16) float lr2[7 * LST];   // R2

    const int t  = threadIdx.x;
    const int wg = blockIdx.x;
    const int b  = wg / 1000;
    const int tl = wg - b * 1000;                  // blk index of this tile
    const int td = tl / 100;
    const int rr = tl - td * 100;
    const int th = rr / 10;
    const int tw = rr - th * 10;

    const float* ip = x + ((size_t)(b*160 + 16*td)) * 25600 + (size_t)(16*th) * 160 + 16*tw;
    float* lllp = bands + ((size_t)(0*2 + b) * 1000 + tl) * 512;

    // ---- phase 1: level-1 forward, 512 positions over 192 threads ----
    #pragma unroll
    for (int k = 0; k < 3; ++k) {
        const int p = t + k * 192;
        if (p < 512) {
            const int q = p >> 6, j = (p >> 3) & 7, w = p & 7;
            const float* pp = ip + (size_t)(2*q) * 25600 + (2*j) * 160 + 2*w;
            float2 q00 = *(const float2*)(pp);
            float2 q01 = *(const float2*)(pp + 160);
            float2 q10 = *(const float2*)(pp + 25600);
            float2 q11 = *(const float2*)(pp + 25600 + 160);
            float wl00 = q00.x + q00.y, wh00 = q00.x - q00.y;
            float wl01 = q01.x + q01.y, wh01 = q01.x - q01.y;
            float wl10 = q10.x + q10.y, wh10 = q10.x - q10.y;
            float wl11 = q11.x + q11.y, wh11 = q11.x - q11.y;
            float hl0l = wl00 + wl01, hh0l = wl00 - wl01;
            float hl0h = wh00 + wh01, hh0h = wh00 - wh01;
            float hl1l = wl10 + wl11, hh1l = wl10 - wl11;
            float hl1h = wh10 + wh11, hh1h = wh10 - wh11;
            lin[0*LST + p] = (hl0h + hl1h) * C3F;   // llh -> band 1
            lin[1*LST + p] = (hh0l + hh1l) * C3F;   // lhl -> band 2
            lin[2*LST + p] = (hh0h + hh1h) * C3F;   // lhh -> band 3
            lin[3*LST + p] = (hl0l - hl1l) * C3F;   // hll -> band 4
            lin[4*LST + p] = (hl0h - hl1h) * C3F;   // hlh -> band 5
            lin[5*LST + p] = (hh0l - hh1l) * C3F;   // hhl -> band 6
            lin[6*LST + p] = (hh0h - hh1h) * C3F;   // hhh -> band 7
            lllp[p] = (hl0l + hl1l) * C3F;          // lll raw, wave-contiguous
        }
    }
    __syncthreads();

    // ---- phase 2: blockproc, 1 slice per thread, normal = wave id ----
    const int wv   = t >> 6;
    const int lane = t & 63;
    const int f    = lane >> 3;   // 0..7 (7 invalid)
    const int s    = lane & 7;
    const bool act = f < 7;
    const int fc   = act ? f : 0;

    float m[64];
    blockproc3(&lin[fc * LST], &lr2[fc * LST], wv, s, act, m);

    // ---- phase 3: wave0 writes processed band (f+1), slice i=s ----
    // 256 B contiguous per thread; 8 threads (s=0..7) fill the 2 KB block.
    if (act && wv == 0) {
        float* base = bands + ((size_t)((f + 1)*2 + b) * 1000 + tl) * 512 + s * 64;
        #pragma unroll
        for (int e = 0; e < 16; ++e) {
            *(float4*)&base[e*4] = make_float4(m[e*4+0]*THIRD, m[e*4+1]*THIRD,
                                               m[e*4+2]*THIRD, m[e*4+3]*THIRD);
        }
    }
}

// ------------------------------------------------------------------
// Kernel B: fused level-2 forward + blockproc + level-2 inverse,
// in place on lll1 (= band 0, block layout). One wg = one 16^3 tile
// of lll1 = 2x2x2 blocks. Grid: 2 * 5^3 = 250 wgs.
// ------------------------------------------------------------------
__global__ __launch_bounds__(192, 4) void l2_pipeline(float* __restrict__ bands) {
    constexpr int LST = 516;
    __shared__ __align__(16) float lin[8 * LST];   // 0 = lll2 raw, 1..7 bands
    __shared__ __align__(16) float lr2[7 * LST];

    const int t  = threadIdx.x;
    const int wg = blockIdx.x;
    const int b  = wg / 125;
    const int tl = wg - b * 125;
    const int td = tl / 25;
    const int rr = tl - td * 25;
    const int th = rr / 5;
    const int tw = rr - th * 5;

    float* band0 = bands + (size_t)b * 1000 * 512;

    // ---- phase 1: level-2 forward, all 8 bands into LDS ----
    #pragma unroll
    for (int k = 0; k < 3; ++k) {
        const int p = t + k * 192;
        if (p < 512) {
            const int q = p >> 6, j = (p >> 3) & 7, w = p & 7;
            // input element (2q+dz, 2j+dy, 2w..2w+1) within the 16^3 tile
            const int e_ = w >> 2;            // Bw sub-block
            const int kk = (2*w) & 7;
            float2 v[2][2];
            #pragma unroll
            for (int dz = 0; dz < 2; ++dz) {
                const int d = 2*q + dz, a = d >> 3, i = d & 7;
                #pragma unroll
                for (int dy = 0; dy < 2; ++dy) {
                    const int h = 2*j + dy, c = h >> 3, jj = h & 7;
                    const size_t blk = (size_t)(2*td + a) * 100 + (2*th + c) * 10 + (2*tw + e_);
                    v[dz][dy] = *(const float2*)&band0[blk * 512 + i*64 + jj*8 + kk];
                }
            }
            float wl00 = v[0][0].x + v[0][0].y, wh00 = v[0][0].x - v[0][0].y;
            float wl01 = v[0][1].x + v[0][1].y, wh01 = v[0][1].x - v[0][1].y;
            float wl10 = v[1][0].x + v[1][0].y, wh10 = v[1][0].x - v[1][0].y;
            float wl11 = v[1][1].x + v[1][1].y, wh11 = v[1][1].x - v[1][1].y;
            float hl0l = wl00 + wl01, hh0l = wl00 - wl01;
            float hl0h = wh00 + wh01, hh0h = wh00 - wh01;
            float hl1l = wl10 + wl11, hh1l = wl10 - wl11;
            float hl1h = wh10 + wh11, hh1h = wh10 - wh11;
            lin[0*LST + p] = (hl0l + hl1l) * C3F;   // lll2 (kept raw)
            lin[1*LST + p] = (hl0h + hl1h) * C3F;
            lin[2*LST + p] = (hh0l + hh1l) * C3F;
            lin[3*LST + p] = (hh0h + hh1h) * C3F;
            lin[4*LST + p] = (hl0l - hl1l) * C3F;
            lin[5*LST + p] = (hl0h - hl1h) * C3F;
            lin[6*LST + p] = (hh0l - hh1l) * C3F;
            lin[7*LST + p] = (hh0h - hh1h) * C3F;
        }
    }
    __syncthreads();

    // ---- phase 2: blockproc bands 1..7 ----
    const int wv   = t >> 6;
    const int lane = t & 63;
    const int f    = lane >> 3;
    const int s    = lane & 7;
    const bool act = f < 7;

    float m[64];
    blockproc3(&lin[(act ? f + 1 : 1) * LST], &lr2[(act ? f : 0) * LST], wv, s, act, m);

    // wave0 writes processed/3 back into lin[band], slice d=s
    if (act && wv == 0) {
        float* Lb = &lin[(f + 1) * LST];
        #pragma unroll
        for (int r = 0; r < 8; ++r) {
            *(float4*)&Lb[s*64 + r*8]     = make_float4(m[r*8+0]*THIRD, m[r*8+1]*THIRD,
                                                        m[r*8+2]*THIRD, m[r*8+3]*THIRD);
            *(float4*)&Lb[s*64 + r*8 + 4] = make_float4(m[r*8+4]*THIRD, m[r*8+5]*THIRD,
                                                        m[r*8+6]*THIRD, m[r*8+7]*THIRD);
        }
    }
    __syncthreads();

    // ---- phase 3: level-2 inverse, write back in place (block layout) ----
    #pragma unroll
    for (int k = 0; k < 3; ++k) {
        const int p = t + k * 192;
        if (p < 512) {
            const int q = p >> 6, j = (p >> 3) & 7, w = p & 7;
            float b0 = lin[0*LST + p], b1 = lin[1*LST + p];
            float b2 = lin[2*LST + p], b3 = lin[3*LST + p];
            float b4 = lin[4*LST + p], b5 = lin[5*LST + p];
            float b6 = lin[6*LST + p], b7 = lin[7*LST + p];
            float c0 = b0 + b4, c1 = b1 + b5, c2 = b2 + b6, c3 = b3 + b7;
            float c4 = b0 - b4, c5 = b1 - b5, c6 = b2 - b6, c7 = b3 - b7;
            float e00 = c0 + c2, e01 = c1 + c3;
            float e02 = c0 - c2, e03 = c1 - c3;
            float e10 = c4 + c6, e11 = c5 + c7;
            float e12 = c4 - c6, e13 = c5 - c7;
            const int e_ = w >> 2;
            const int kk = (2*w) & 7;
            #pragma unroll
            for (int dz = 0; dz < 2; ++dz) {
                const int d = 2*q + dz, a = d >> 3, i = d & 7;
                const float ex0 = dz ? e10 : e00, ex1 = dz ? e11 : e01;
                const float ex2 = dz ? e12 : e02, ex3 = dz ? e13 : e03;
                #pragma unroll
                for (int dy = 0; dy < 2; ++dy) {
                    const int h = 2*j + dy, c = h >> 3, jj = h & 7;
                    const float lo = dy ? ex2 : ex0, hi = dy ? ex3 : ex1;
                    const size_t blk = (size_t)(2*td + a) * 100 + (2*th + c) * 10 + (2*tw + e_);
                    *(float2*)&band0[blk * 512 + i*64 + jj*8 + kk] =
                        make_float2((lo + hi) * C3F, (lo - hi) * C3F);
                }
            }
        }
    }
}

// ------------------------------------------------------------------
// Kernel C: level-1 inverse, block-layout bands -> volume out (2,160^3).
// One wg (256 thr) = 2 adjacent-Bw blocks (so each 128-B output line
// is produced by one wg). Grid: 2 * 10*10*5 = 1000 wgs.
// ------------------------------------------------------------------
__global__ __launch_bounds__(256) void dwt3_inv80(const float* __restrict__ bands,
                                                  float* __restrict__ out) {
    const int t  = threadIdx.x;
    const int wg = blockIdx.x;
    const int b   = wg / 500;
    const int r0  = wg - b * 500;
    const int Bd  = r0 / 50;
    const int r1  = r0 - Bd * 50;
    const int Bh  = r1 / 5;
    const int Bwp = r1 - Bh * 5;

    const int p0 = 2 * t;                 // even position in [0,512)
    const int q  = p0 >> 6, j = (p0 >> 3) & 7, w0 = p0 & 7;   // w0 even

    #pragma unroll
    for (int e = 0; e < 2; ++e) {
        const int Bw = 2 * Bwp + e;
        const size_t blk = (size_t)Bd * 100 + Bh * 10 + Bw;

        float2 B0, B1, B2, B3, B4, B5, B6, B7;
        {
            const float* bp = bands + ((size_t)b * 1000 + blk) * 512 + p0;
            constexpr size_t FS = (size_t)2 * 1000 * 512;   // per-band stride
            B0 = *(const float2*)(bp + 0*FS);
            B1 = *(const float2*)(bp + 1*FS);
            B2 = *(const float2*)(bp + 2*FS);
            B3 = *(const float2*)(bp + 3*FS);
            B4 = *(const float2*)(bp + 4*FS);
            B5 = *(const float2*)(bp + 5*FS);
            B6 = *(const float2*)(bp + 6*FS);
            B7 = *(const float2*)(bp + 7*FS);
        }

        float c0x = B0.x + B4.x, c1x = B1.x + B5.x, c2x = B2.x + B6.x, c3x = B3.x + B7.x;
        float c4x = B0.x - B4.x, c5x = B1.x - B5.x, c6x = B2.x - B6.x, c7x = B3.x - B7.x;
        float e00x = c0x + c2x, e01x = c1x + c3x, e02x = c0x - c2x, e03x = c1x - c3x;
        float e10x = c4x + c6x, e11x = c5x + c7x, e12x = c4x - c6x, e13x = c5x - c7x;

        float c0y = B0.y + B4.y, c1y = B1.y + B5.y, c2y = B2.y + B6.y, c3y = B3.y + B7.y;
        float c4y = B0.y - B4.y, c5y = B1.y - B5.y, c6y = B2.y - B6.y, c7y = B3.y - B7.y;
        float e00y = c0y + c2y, e01y = c1y + c3y, e02y = c0y - c2y, e03y = c1y - c3y;
        float e10y = c4y + c6y, e11y = c5y + c7y, e12y = c4y - c6y, e13y = c5y - c7y;

        // output element base: (16Bd+2q, 16Bh+2j, 16Bw+2w0)
        float* p = out + (((size_t)b * 160 + 16*Bd + 2*q) * 160 + 16*Bh + 2*j) * 160
                       + 16*Bw + 2*w0;
        floatx4 o0 = { (e00x+e01x)*C3F, (e00x-e01x)*C3F, (e00y+e01y)*C3F, (e00y-e01y)*C3F };
        floatx4 o1 = { (e02x+e03x)*C3F, (e02x-e03x)*C3F, (e02y+e03y)*C3F, (e02y-e03y)*C3F };
        floatx4 o2 = { (e10x+e11x)*C3F, (e10x-e11x)*C3F, (e10y+e11y)*C3F, (e10y-e11y)*C3F };
        floatx4 o3 = { (e12x+e13x)*C3F, (e12x-e13x)*C3F, (e12y+e13y)*C3F, (e12y-e13y)*C3F };
        __builtin_nontemporal_store(o0, (floatx4*)(p));
        __builtin_nontemporal_store(o1, (floatx4*)(p + 160));
        __builtin_nontemporal_store(o2, (floatx4*)(p + 25600));
        __builtin_nontemporal_store(o3, (floatx4*)(p + 25600 + 160));
    }
}

// ------------------------------------------------------------------
// Pipeline (3 launches):
//   A: x (2,160^3) -> band0 = lll1 raw (block layout), bands 1..7 processed
//   B: band0 -> fwd2 + blockproc + inv2, in place (LDS-resident)
//   C: bands 0..7 (block layout) -> inverse level-1 -> d_out (volume)
// ------------------------------------------------------------------
extern "C" void kernel_launch(void* const* d_in, const int* in_sizes, int n_in,
                              void* d_out, int out_size, void* d_ws, size_t ws_size,
                              hipStream_t stream) {
    const float* x = (const float*)d_in[0];
    float* out = (float*)d_out;
    float* bands = (float*)d_ws;   // 8 bands * 2 * 1000 blocks * 512 floats = 32.77 MB

    fwd1_bp<<<2000, 192, 0, stream>>>(x, bands);
    l2_pipeline<<<250, 192, 0, stream>>>(bands);
    dwt3_inv80<<<1000, 256, 0, stream>>>(bands, out);
}

// Round 4
// 111.564 us; speedup vs baseline: 1.0780x; 1.0539x over previous
//
#include <hip/hip_runtime.h>

#define IS2 0.7071067811865476f
#define C3F 0.35355339059327373f   // (1/sqrt(2))^3
#define TAU_F 0.05f
#define THIRD 0.3333333333333333f

typedef float floatx4 __attribute__((ext_vector_type(4)));

// ------------------------------------------------------------------
// In-place 2D multilevel Haar on an 8x8 register tile (<=32-float temps).
// Matches reference _haar2_fwd / _haar2_inv.
// ------------------------------------------------------------------
__device__ __forceinline__ void haar2_fwd(float (&m)[64]) {
    #pragma unroll
    for (int half = 4; half >= 1; half >>= 1) {
        const int sz = half * 2;
        float th[32];
        #pragma unroll
        for (int r = 0; r < half; ++r)
            #pragma unroll
            for (int c = 0; c < sz; ++c) {
                float a = m[(2*r)*8 + c], b = m[(2*r+1)*8 + c];
                m[r*8 + c] = (a + b) * IS2;
                th[r*8 + c] = (a - b) * IS2;
            }
        #pragma unroll
        for (int r = 0; r < half; ++r)
            #pragma unroll
            for (int c = 0; c < sz; ++c) m[(r+half)*8 + c] = th[r*8 + c];
        #pragma unroll
        for (int r = 0; r < sz; ++r) {
            float tw[4];
            #pragma unroll
            for (int c = 0; c < half; ++c) {
                float a = m[r*8 + 2*c], b = m[r*8 + 2*c + 1];
                m[r*8 + c] = (a + b) * IS2;
                tw[c]      = (a - b) * IS2;
            }
            #pragma unroll
            for (int c = 0; c < half; ++c) m[r*8 + c + half] = tw[c];
        }
    }
}

__device__ __forceinline__ void haar2_inv(float (&m)[64]) {
    #pragma unroll
    for (int sz = 2; sz <= 8; sz <<= 1) {
        const int half = sz >> 1;
        #pragma unroll
        for (int r = 0; r < sz; ++r) {
            float te[8];
            #pragma unroll
            for (int c = 0; c < half; ++c) {
                float lo = m[r*8 + c], hi = m[r*8 + c + half];
                te[2*c]   = (lo + hi) * IS2;
                te[2*c+1] = (lo - hi) * IS2;
            }
            #pragma unroll
            for (int k = 0; k < sz; ++k) m[r*8 + k] = te[k];
        }
        #pragma unroll
        for (int c = 0; c < sz; ++c) {
            float tc[8];
            #pragma unroll
            for (int r = 0; r < half; ++r) {
                float lo = m[r*8 + c], hi = m[(r+half)*8 + c];
                tc[2*r]   = (lo + hi) * IS2;
                tc[2*r+1] = (lo - hi) * IS2;
            }
            #pragma unroll
            for (int r = 0; r < sz; ++r) m[r*8 + c] = tc[r];
        }
    }
}

__device__ __forceinline__ void bandlet_slice(float (&m)[64]) {
    haar2_fwd(m);
    float dc = m[0];
    #pragma unroll
    for (int e = 0; e < 64; ++e) {
        float v = m[e];
        float av = fabsf(v) - TAU_F;
        m[e] = av > 0.0f ? copysignf(av, v) : 0.0f;
    }
    m[0] = dc;
    haar2_inv(m);
}

// ------------------------------------------------------------------
// 3-wave blockproc on one 8^3 band block (PLAIN layout in LDS:
//   element (d,h,w) at Lb[d*64 + h*8 + w], band stride 516 dwords).
// wv0: slice d=s, keeps R0 in m (accumulator). wv1: slice h=s, writes
// R1 back into Lb. wv2: slice w=s, scatters R2 into Rb.
// After return, wv0&&act threads hold m = R0+R1+R2 for slice d=s.
// ALL threads of the block must call (barriers inside); waves >=3 and
// f==7 threads pass act=false and just participate in barriers.
// ------------------------------------------------------------------
__device__ __forceinline__ void blockproc3(float* __restrict__ Lb,
                                           float* __restrict__ Rb,
                                           int wv, int s, bool act,
                                           float (&m)[64]) {
    if (act) {
        if (wv == 0) {
            #pragma unroll
            for (int r = 0; r < 8; ++r) {
                float4 v0 = *(const float4*)&Lb[s*64 + r*8];
                float4 v1 = *(const float4*)&Lb[s*64 + r*8 + 4];
                m[r*8+0]=v0.x; m[r*8+1]=v0.y; m[r*8+2]=v0.z; m[r*8+3]=v0.w;
                m[r*8+4]=v1.x; m[r*8+5]=v1.y; m[r*8+6]=v1.z; m[r*8+7]=v1.w;
            }
        } else if (wv == 1) {
            #pragma unroll
            for (int r = 0; r < 8; ++r) {
                float4 v0 = *(const float4*)&Lb[r*64 + s*8];
                float4 v1 = *(const float4*)&Lb[r*64 + s*8 + 4];
                m[r*8+0]=v0.x; m[r*8+1]=v0.y; m[r*8+2]=v0.z; m[r*8+3]=v0.w;
                m[r*8+4]=v1.x; m[r*8+5]=v1.y; m[r*8+6]=v1.z; m[r*8+7]=v1.w;
            }
        } else {
            #pragma unroll
            for (int r = 0; r < 8; ++r)
                #pragma unroll
                for (int c = 0; c < 8; ++c)
                    m[r*8+c] = Lb[r*64 + c*8 + s];
        }
    }
    __syncthreads();          // all loads of Lb drained -> Lb reusable
    if (act) {
        bandlet_slice(m);
        if (wv == 1) {
            #pragma unroll
            for (int r = 0; r < 8; ++r) {
                *(float4*)&Lb[r*64 + s*8]     = make_float4(m[r*8+0], m[r*8+1], m[r*8+2], m[r*8+3]);
                *(float4*)&Lb[r*64 + s*8 + 4] = make_float4(m[r*8+4], m[r*8+5], m[r*8+6], m[r*8+7]);
            }
        } else if (wv == 2) {
            #pragma unroll
            for (int r = 0; r < 8; ++r)
                #pragma unroll
                for (int c = 0; c < 8; ++c)
                    Rb[r*64 + c*8 + s] = m[r*8+c];
        }
    }
    __syncthreads();          // R1/R2 visible
    if (act && wv == 0) {
        #pragma unroll
        for (int r = 0; r < 8; ++r) {
            float4 a0 = *(const float4*)&Lb[s*64 + r*8];
            float4 a1 = *(const float4*)&Lb[s*64 + r*8 + 4];
            float4 b0 = *(const float4*)&Rb[s*64 + r*8];
            float4 b1 = *(const float4*)&Rb[s*64 + r*8 + 4];
            m[r*8+0] += a0.x + b0.x; m[r*8+1] += a0.y + b0.y;
            m[r*8+2] += a0.z + b0.z; m[r*8+3] += a0.w + b0.w;
            m[r*8+4] += a1.x + b1.x; m[r*8+5] += a1.y + b1.y;
            m[r*8+6] += a1.z + b1.z; m[r*8+7] += a1.w + b1.w;
        }
    }
}

// ==================================================================
// Intermediate band storage: BLOCK-NATIVE layout.
//   bands[ ((f*2 + b)*1000 + blk) * 512 + i*64 + j*8 + k ]
// blk = Bd*100 + Bh*10 + Bw. Every 8^3 block is 2 KB contiguous.
//
// XCD swizzle: dispatch round-robins blockIdx%8 across XCDs.
//   A: tile id = (g&7)*250 + (g>>3)   (2000 = 8*250)
//   C: pair id = (g&7)*125 + (g>>3)   (1000 = 8*125)
// C's pair id covers A tiles {2*id, 2*id+1} -> same /250 bucket ->
// reader XCD == writer XCD for band data; w-adjacent A tiles share an
// XCD -> each 128-B input line fetched into exactly one L2.
// ==================================================================

// ------------------------------------------------------------------
// Kernel A: fused level-1 forward DWT + level-1 blockproc.
// One wg (192 thr) = one 16^3 input tile. Grid: 2000.
// ------------------------------------------------------------------
__global__ __launch_bounds__(192, 4) void fwd1_bp(const float* __restrict__ x,
                                                  float* __restrict__ bands) {
    constexpr int LST = 516;
    __shared__ __align__(16) float lin[7 * LST];   // bands 1..7, reused as R1
    __shared__ __align__(16) float lr2[7 * LST];   // R2

    const int t  = threadIdx.x;
    const int g  = blockIdx.x;
    const int id = (g & 7) * 250 + (g >> 3);       // XCD-contiguous tile id
    const int b  = id / 1000;
    const int tl = id - b * 1000;                  // blk index of this tile
    const int td = tl / 100;
    const int rr = tl - td * 100;
    const int th = rr / 10;
    const int tw = rr - th * 10;

    const float* ip = x + ((size_t)(b*160 + 16*td)) * 25600 + (size_t)(16*th) * 160 + 16*tw;
    float* lllp = bands + ((size_t)(0*2 + b) * 1000 + tl) * 512;

    // ---- phase 1: level-1 forward; 256 jobs (q,j,wp), float4 loads,
    //      each job produces outputs w=2wp and w=2wp+1 ----
    #pragma unroll
    for (int k = 0; k < 2; ++k) {
        const int p = t + k * 192;
        if (p < 256) {
            const int q = p >> 5, j = (p >> 2) & 7, wp = p & 3;
            const float* pp = ip + (size_t)(2*q) * 25600 + (2*j) * 160 + 4*wp;
            floatx4 q00 = *(const floatx4*)(pp);
            floatx4 q01 = *(const floatx4*)(pp + 160);
            floatx4 q10 = *(const floatx4*)(pp + 25600);
            floatx4 q11 = *(const floatx4*)(pp + 25600 + 160);
            const int pos0 = q*64 + j*8 + 2*wp;
            float2 r1, r2, r3, r4, r5, r6, r7, r0;
            #pragma unroll
            for (int e = 0; e < 2; ++e) {
                const float a00 = e ? q00.z : q00.x, b00 = e ? q00.w : q00.y;
                const float a01 = e ? q01.z : q01.x, b01 = e ? q01.w : q01.y;
                const float a10 = e ? q10.z : q10.x, b10 = e ? q10.w : q10.y;
                const float a11 = e ? q11.z : q11.x, b11 = e ? q11.w : q11.y;
                float wl00 = a00 + b00, wh00 = a00 - b00;
                float wl01 = a01 + b01, wh01 = a01 - b01;
                float wl10 = a10 + b10, wh10 = a10 - b10;
                float wl11 = a11 + b11, wh11 = a11 - b11;
                float hl0l = wl00 + wl01, hh0l = wl00 - wl01;
                float hl0h = wh00 + wh01, hh0h = wh00 - wh01;
                float hl1l = wl10 + wl11, hh1l = wl10 - wl11;
                float hl1h = wh10 + wh11, hh1h = wh10 - wh11;
                float* d1 = e ? &r1.y : &r1.x; *d1 = (hl0h + hl1h) * C3F;
                float* d2 = e ? &r2.y : &r2.x; *d2 = (hh0l + hh1l) * C3F;
                float* d3 = e ? &r3.y : &r3.x; *d3 = (hh0h + hh1h) * C3F;
                float* d4 = e ? &r4.y : &r4.x; *d4 = (hl0l - hl1l) * C3F;
                float* d5 = e ? &r5.y : &r5.x; *d5 = (hl0h - hl1h) * C3F;
                float* d6 = e ? &r6.y : &r6.x; *d6 = (hh0l - hh1l) * C3F;
                float* d7 = e ? &r7.y : &r7.x; *d7 = (hh0h - hh1h) * C3F;
                float* d0 = e ? &r0.y : &r0.x; *d0 = (hl0l + hl1l) * C3F;
            }
            *(float2*)&lin[0*LST + pos0] = r1;   // llh -> band 1
            *(float2*)&lin[1*LST + pos0] = r2;   // lhl -> band 2
            *(float2*)&lin[2*LST + pos0] = r3;   // lhh -> band 3
            *(float2*)&lin[3*LST + pos0] = r4;   // hll -> band 4
            *(float2*)&lin[4*LST + pos0] = r5;   // hlh -> band 5
            *(float2*)&lin[5*LST + pos0] = r6;   // hhl -> band 6
            *(float2*)&lin[6*LST + pos0] = r7;   // hhh -> band 7
            *(float2*)&lllp[pos0] = r0;          // lll raw, contiguous block
        }
    }
    __syncthreads();

    // ---- phase 2: blockproc, 1 slice per thread, normal = wave id ----
    const int wv   = t >> 6;
    const int lane = t & 63;
    const int f    = lane >> 3;   // 0..7 (7 invalid)
    const int s    = lane & 7;
    const bool act = f < 7;
    const int fc   = act ? f : 0;

    float m[64];
    blockproc3(&lin[fc * LST], &lr2[fc * LST], wv, s, act, m);

    // ---- phase 3: wave0 writes processed band (f+1), slice i=s ----
    if (act && wv == 0) {
        float* base = bands + ((size_t)((f + 1)*2 + b) * 1000 + tl) * 512 + s * 64;
        #pragma unroll
        for (int e = 0; e < 16; ++e) {
            *(float4*)&base[e*4] = make_float4(m[e*4+0]*THIRD, m[e*4+1]*THIRD,
                                               m[e*4+2]*THIRD, m[e*4+3]*THIRD);
        }
    }
}

// ------------------------------------------------------------------
// Kernel B: fused level-2 forward + blockproc + level-2 inverse,
// in place on lll1 (= band 0, block layout). One wg (512 thr = 8 waves)
// = one 16^3 tile of lll1 = 2x2x2 blocks. Grid: 250 wgs.
// 8 waves hide latency in the memory phases; waves 3..7 idle through
// the short blockproc compute.
// ------------------------------------------------------------------
__global__ __launch_bounds__(512, 2) void l2_pipeline(float* __restrict__ bands) {
    constexpr int LST = 516;
    __shared__ __align__(16) float lin[8 * LST];   // 0 = lll2 raw, 1..7 bands
    __shared__ __align__(16) float lr2[7 * LST];

    const int t  = threadIdx.x;
    const int wg = blockIdx.x;
    const int b  = wg / 125;
    const int tl = wg - b * 125;
    const int td = tl / 25;
    const int rr = tl - td * 25;
    const int th = rr / 5;
    const int tw = rr - th * 5;

    float* band0 = bands + (size_t)b * 1000 * 512;

    // ---- phase 1: level-2 forward, all 8 bands into LDS (512 jobs) ----
    {
        const int p = t;
        const int q = p >> 6, j = (p >> 3) & 7, w = p & 7;
        const int e_ = w >> 2;            // Bw sub-block
        const int kk = (2*w) & 7;
        float2 v[2][2];
        #pragma unroll
        for (int dz = 0; dz < 2; ++dz) {
            const int d = 2*q + dz, a = d >> 3, i = d & 7;
            #pragma unroll
            for (int dy = 0; dy < 2; ++dy) {
                const int h = 2*j + dy, c = h >> 3, jj = h & 7;
                const size_t blk = (size_t)(2*td + a) * 100 + (2*th + c) * 10 + (2*tw + e_);
                v[dz][dy] = *(const float2*)&band0[blk * 512 + i*64 + jj*8 + kk];
            }
        }
        float wl00 = v[0][0].x + v[0][0].y, wh00 = v[0][0].x - v[0][0].y;
        float wl01 = v[0][1].x + v[0][1].y, wh01 = v[0][1].x - v[0][1].y;
        float wl10 = v[1][0].x + v[1][0].y, wh10 = v[1][0].x - v[1][0].y;
        float wl11 = v[1][1].x + v[1][1].y, wh11 = v[1][1].x - v[1][1].y;
        float hl0l = wl00 + wl01, hh0l = wl00 - wl01;
        float hl0h = wh00 + wh01, hh0h = wh00 - wh01;
        float hl1l = wl10 + wl11, hh1l = wl10 - wl11;
        float hl1h = wh10 + wh11, hh1h = wh10 - wh11;
        lin[0*LST + p] = (hl0l + hl1l) * C3F;   // lll2 (kept raw)
        lin[1*LST + p] = (hl0h + hl1h) * C3F;
        lin[2*LST + p] = (hh0l + hh1l) * C3F;
        lin[3*LST + p] = (hh0h + hh1h) * C3F;
        lin[4*LST + p] = (hl0l - hl1l) * C3F;
        lin[5*LST + p] = (hl0h - hl1h) * C3F;
        lin[6*LST + p] = (hh0l - hh1l) * C3F;
        lin[7*LST + p] = (hh0h - hh1h) * C3F;
    }
    __syncthreads();

    // ---- phase 2: blockproc bands 1..7 (waves 0..2 active) ----
    const int wv   = t >> 6;
    const int lane = t & 63;
    const int f    = lane >> 3;
    const int s    = lane & 7;
    const bool act = (wv < 3) && (f < 7);
    const int fc   = (f < 7) ? f : 0;

    float m[64];
    blockproc3(&lin[(fc + 1) * LST], &lr2[fc * LST], wv, s, act, m);

    // wave0 writes processed/3 back into lin[band], slice d=s
    if (act && wv == 0) {
        float* Lb = &lin[(f + 1) * LST];
        #pragma unroll
        for (int r = 0; r < 8; ++r) {
            *(float4*)&Lb[s*64 + r*8]     = make_float4(m[r*8+0]*THIRD, m[r*8+1]*THIRD,
                                                        m[r*8+2]*THIRD, m[r*8+3]*THIRD);
            *(float4*)&Lb[s*64 + r*8 + 4] = make_float4(m[r*8+4]*THIRD, m[r*8+5]*THIRD,
                                                        m[r*8+6]*THIRD, m[r*8+7]*THIRD);
        }
    }
    __syncthreads();

    // ---- phase 3: level-2 inverse, write back in place (512 jobs) ----
    {
        const int p = t;
        const int q = p >> 6, j = (p >> 3) & 7, w = p & 7;
        float b0 = lin[0*LST + p], b1 = lin[1*LST + p];
        float b2 = lin[2*LST + p], b3 = lin[3*LST + p];
        float b4 = lin[4*LST + p], b5 = lin[5*LST + p];
        float b6 = lin[6*LST + p], b7 = lin[7*LST + p];
        float c0 = b0 + b4, c1 = b1 + b5, c2 = b2 + b6, c3 = b3 + b7;
        float c4 = b0 - b4, c5 = b1 - b5, c6 = b2 - b6, c7 = b3 - b7;
        float e00 = c0 + c2, e01 = c1 + c3;
        float e02 = c0 - c2, e03 = c1 - c3;
        float e10 = c4 + c6, e11 = c5 + c7;
        float e12 = c4 - c6, e13 = c5 - c7;
        const int e_ = w >> 2;
        const int kk = (2*w) & 7;
        #pragma unroll
        for (int dz = 0; dz < 2; ++dz) {
            const int d = 2*q + dz, a = d >> 3, i = d & 7;
            const float ex0 = dz ? e10 : e00, ex1 = dz ? e11 : e01;
            const float ex2 = dz ? e12 : e02, ex3 = dz ? e13 : e03;
            #pragma unroll
            for (int dy = 0; dy < 2; ++dy) {
                const int h = 2*j + dy, c = h >> 3, jj = h & 7;
                const float lo = dy ? ex2 : ex0, hi = dy ? ex3 : ex1;
                const size_t blk = (size_t)(2*td + a) * 100 + (2*th + c) * 10 + (2*tw + e_);
                *(float2*)&band0[blk * 512 + i*64 + jj*8 + kk] =
                    make_float2((lo + hi) * C3F, (lo - hi) * C3F);
            }
        }
    }
}

// ------------------------------------------------------------------
// Kernel C: level-1 inverse, block-layout bands -> volume out (2,160^3).
// One wg (256 thr) = 2 adjacent-Bw blocks. Grid: 1000 wgs, XCD-swizzled
// to match kernel A's writer XCDs.
// ------------------------------------------------------------------
__global__ __launch_bounds__(256) void dwt3_inv80(const float* __restrict__ bands,
                                                  float* __restrict__ out) {
    const int t  = threadIdx.x;
    const int g  = blockIdx.x;
    const int id = (g & 7) * 125 + (g >> 3);   // XCD-contiguous pair id
    const int b   = id / 500;
    const int r0  = id - b * 500;
    const int Bd  = r0 / 50;
    const int r1  = r0 - Bd * 50;
    const int Bh  = r1 / 5;
    const int Bwp = r1 - Bh * 5;

    const int p0 = 2 * t;                 // even position in [0,512)
    const int q  = p0 >> 6, j = (p0 >> 3) & 7, w0 = p0 & 7;   // w0 even

    #pragma unroll
    for (int e = 0; e < 2; ++e) {
        const int Bw = 2 * Bwp + e;
        const size_t blk = (size_t)Bd * 100 + Bh * 10 + Bw;

        float2 B0, B1, B2, B3, B4, B5, B6, B7;
        {
            const float* bp = bands + ((size_t)b * 1000 + blk) * 512 + p0;
            constexpr size_t FS = (size_t)2 * 1000 * 512;   // per-band stride
            B0 = *(const float2*)(bp + 0*FS);
            B1 = *(const float2*)(bp + 1*FS);
            B2 = *(const float2*)(bp + 2*FS);
            B3 = *(const float2*)(bp + 3*FS);
            B4 = *(const float2*)(bp + 4*FS);
            B5 = *(const float2*)(bp + 5*FS);
            B6 = *(const float2*)(bp + 6*FS);
            B7 = *(const float2*)(bp + 7*FS);
        }

        float c0x = B0.x + B4.x, c1x = B1.x + B5.x, c2x = B2.x + B6.x, c3x = B3.x + B7.x;
        float c4x = B0.x - B4.x, c5x = B1.x - B5.x, c6x = B2.x - B6.x, c7x = B3.x - B7.x;
        float e00x = c0x + c2x, e01x = c1x + c3x, e02x = c0x - c2x, e03x = c1x - c3x;
        float e10x = c4x + c6x, e11x = c5x + c7x, e12x = c4x - c6x, e13x = c5x - c7x;

        float c0y = B0.y + B4.y, c1y = B1.y + B5.y, c2y = B2.y + B6.y, c3y = B3.y + B7.y;
        float c4y = B0.y - B4.y, c5y = B1.y - B5.y, c6y = B2.y - B6.y, c7y = B3.y - B7.y;
        float e00y = c0y + c2y, e01y = c1y + c3y, e02y = c0y - c2y, e03y = c1y - c3y;
        float e10y = c4y + c6y, e11y = c5y + c7y, e12y = c4y - c6y, e13y = c5y - c7y;

        // output element base: (16Bd+2q, 16Bh+2j, 16Bw+2w0)
        float* p = out + (((size_t)b * 160 + 16*Bd + 2*q) * 160 + 16*Bh + 2*j) * 160
                       + 16*Bw + 2*w0;
        floatx4 o0 = { (e00x+e01x)*C3F, (e00x-e01x)*C3F, (e00y+e01y)*C3F, (e00y-e01y)*C3F };
        floatx4 o1 = { (e02x+e03x)*C3F, (e02x-e03x)*C3F, (e02y+e03y)*C3F, (e02y-e03y)*C3F };
        floatx4 o2 = { (e10x+e11x)*C3F, (e10x-e11x)*C3F, (e10y+e11y)*C3F, (e10y-e11y)*C3F };
        floatx4 o3 = { (e12x+e13x)*C3F, (e12x-e13x)*C3F, (e12y+e13y)*C3F, (e12y-e13y)*C3F };
        __builtin_nontemporal_store(o0, (floatx4*)(p));
        __builtin_nontemporal_store(o1, (floatx4*)(p + 160));
        __builtin_nontemporal_store(o2, (floatx4*)(p + 25600));
        __builtin_nontemporal_store(o3, (floatx4*)(p + 25600 + 160));
    }
}

// ------------------------------------------------------------------
// Pipeline (3 launches):
//   A: x (2,160^3) -> band0 = lll1 raw (block layout), bands 1..7 processed
//   B: band0 -> fwd2 + blockproc + inv2, in place (LDS-resident)
//   C: bands 0..7 (block layout) -> inverse level-1 -> d_out (volume)
// ------------------------------------------------------------------
extern "C" void kernel_launch(void* const* d_in, const int* in_sizes, int n_in,
                              void* d_out, int out_size, void* d_ws, size_t ws_size,
                              hipStream_t stream) {
    const float* x = (const float*)d_in[0];
    float* out = (float*)d_out;
    float* bands = (float*)d_ws;   // 8 bands * 2 * 1000 blocks * 512 floats = 32.77 MB

    fwd1_bp<<<2000, 192, 0, stream>>>(x, bands);
    l2_pipeline<<<250, 512, 0, stream>>>(bands);
    dwt3_inv80<<<1000, 256, 0, stream>>>(bands, out);
}